// Round 1
// baseline (632.862 us; speedup 1.0000x reference)
//
#include <hip/hip_runtime.h>

#define F1 128
#define F2 8

// ---------- degree histogram ----------
__global__ void k_degrees(const int* __restrict__ src, const int* __restrict__ dst,
                          int* __restrict__ deg_out, int* __restrict__ deg_in, int E) {
  int e = blockIdx.x * 256 + threadIdx.x;
  if (e < E) {
    atomicAdd(&deg_out[src[e]], 1);
    atomicAdd(&deg_in[dst[e]], 1);
  }
}

// ---------- norms + per-graph node counts ----------
__global__ void k_norms(const int* __restrict__ deg_out, const int* __restrict__ deg_in,
                        const int* __restrict__ gids,
                        float* __restrict__ norm_src, float* __restrict__ norm_dst,
                        int* __restrict__ gcnt, int N) {
  int n = blockIdx.x * 256 + threadIdx.x;
  if (n < N) {
    int dout = deg_out[n], din = deg_in[n];
    norm_src[n] = dout > 0 ? rsqrtf((float)dout) : 0.f;
    norm_dst[n] = din > 0 ? rsqrtf((float)din) : 0.f;
    atomicAdd(&gcnt[gids[n]], 1);
  }
}

// ---------- single-block exclusive scan of deg_in -> CSR offsets ----------
__global__ __launch_bounds__(1024) void k_scan(const int* __restrict__ deg_in,
                                               int* __restrict__ off, int* __restrict__ cursor,
                                               int N) {
  __shared__ int sums[1024];
  int t = threadIdx.x;
  int chunk = (N + 1023) / 1024;
  int base = t * chunk;
  int s = 0;
  for (int i = 0; i < chunk; ++i) {
    int idx = base + i;
    if (idx < N) s += deg_in[idx];
  }
  sums[t] = s;
  __syncthreads();
  // Hillis-Steele inclusive scan
  for (int d = 1; d < 1024; d <<= 1) {
    int v = (t >= d) ? sums[t - d] : 0;
    __syncthreads();
    sums[t] += v;
    __syncthreads();
  }
  int run = (t == 0) ? 0 : sums[t - 1];
  for (int i = 0; i < chunk; ++i) {
    int idx = base + i;
    if (idx < N) {
      off[idx] = run;
      cursor[idx] = run;
      run += deg_in[idx];
    }
  }
  if (t == 1023) off[N] = run;
}

// ---------- bucket edges by destination: esrc[p] = src ----------
__global__ void k_bucket(const int* __restrict__ src, const int* __restrict__ dst,
                         int* __restrict__ cursor, int* __restrict__ esrc, int E) {
  int e = blockIdx.x * 256 + threadIdx.x;
  if (e < E) {
    int p = atomicAdd(&cursor[dst[e]], 1);
    esrc[p] = src[e];
  }
}

// ---------- GEMM1: h1n[n][c] = (sum_k x[n][k] W1[k][c]) * norm_src[n] ----------
// 64 rows x 64 cols per block; W tile (32KB) + transposed x tile (32KB) in LDS;
// 4x4 register tile per thread -> 2 ds_read_b128 per 16 v_fma (VALU-bound).
__global__ __launch_bounds__(256) void k_gemm1(const float* __restrict__ x,
                                               const float* __restrict__ W1,
                                               const float* __restrict__ norm_src,
                                               float* __restrict__ h1n, int N) {
  __shared__ float Wlds[128 * 64];   // [k][cc]
  __shared__ float xsT[128 * 64];    // [k][r]  (transposed -> b128 over rows)
  int row0 = blockIdx.x * 64;
  int c0 = blockIdx.y * 64;
  int tid = threadIdx.x;

  // load W tile: 2048 float4
  for (int i = tid; i < 2048; i += 256) {
    int k = i >> 4;
    int cc = (i & 15) << 2;
    *(float4*)&Wlds[k * 64 + cc] = *(const float4*)&W1[k * 128 + c0 + cc];
  }
  // load x tile, transposed into LDS (conflict-free scalar writes: bank = r%32)
  for (int i = tid; i < 2048; i += 256) {
    int r = i & 63;
    int kb = (i >> 6) << 2;
    int grow = row0 + r;
    float4 v = make_float4(0.f, 0.f, 0.f, 0.f);
    if (grow < N) v = *(const float4*)&x[(size_t)grow * 128 + kb];
    xsT[(kb + 0) * 64 + r] = v.x;
    xsT[(kb + 1) * 64 + r] = v.y;
    xsT[(kb + 2) * 64 + r] = v.z;
    xsT[(kb + 3) * 64 + r] = v.w;
  }
  __syncthreads();

  int tc = tid & 15;   // 16 col groups of 4
  int tr = tid >> 4;   // 16 row groups of 4
  float acc[4][4] = {{0.f}};
#pragma unroll 4
  for (int k = 0; k < 128; ++k) {
    float4 xv = *(const float4*)&xsT[k * 64 + tr * 4];
    float4 wv = *(const float4*)&Wlds[k * 64 + tc * 4];
    acc[0][0] += xv.x * wv.x; acc[0][1] += xv.x * wv.y; acc[0][2] += xv.x * wv.z; acc[0][3] += xv.x * wv.w;
    acc[1][0] += xv.y * wv.x; acc[1][1] += xv.y * wv.y; acc[1][2] += xv.y * wv.z; acc[1][3] += xv.y * wv.w;
    acc[2][0] += xv.z * wv.x; acc[2][1] += xv.z * wv.y; acc[2][2] += xv.z * wv.z; acc[2][3] += xv.z * wv.w;
    acc[3][0] += xv.w * wv.x; acc[3][1] += xv.w * wv.y; acc[3][2] += xv.w * wv.z; acc[3][3] += xv.w * wv.w;
  }
#pragma unroll
  for (int i = 0; i < 4; ++i) {
    int grow = row0 + tr * 4 + i;
    if (grow < N) {
      float ns = norm_src[grow];
      float4 o = make_float4(acc[i][0] * ns, acc[i][1] * ns, acc[i][2] * ns, acc[i][3] * ns);
      *(float4*)&h1n[(size_t)grow * 128 + c0 + tc * 4] = o;
    }
  }
}

// ---------- layer-1 aggregation: one wave per dst node, gather-form (no atomics) ----------
// h1b[n] = relu( (sum_{e: dst=n} h1n[src_e]) * norm_dst[n] + b1 )
__global__ __launch_bounds__(256) void k_agg1(const float* __restrict__ h1n,
                                              const int* __restrict__ off,
                                              const int* __restrict__ esrc,
                                              const float* __restrict__ norm_dst,
                                              const float* __restrict__ b1,
                                              float* __restrict__ h1b, int N) {
  int wid = (blockIdx.x * 256 + threadIdx.x) >> 6;
  int lane = threadIdx.x & 63;
  if (wid >= N) return;
  int i0 = off[wid], i1 = off[wid + 1];
  float2 acc = make_float2(0.f, 0.f);
  for (int i = i0; i < i1; i += 64) {
    int cnt = min(64, i1 - i);
    int eid = (i + lane < i1) ? esrc[i + lane] : 0;
    for (int t = 0; t < cnt; ++t) {
      int s = __shfl(eid, t);
      float2 v = *(const float2*)&h1n[(size_t)s * 128 + lane * 2];
      acc.x += v.x;
      acc.y += v.y;
    }
  }
  float nd = norm_dst[wid];
  float2 bb = *(const float2*)&b1[lane * 2];
  float ox = fmaxf(acc.x * nd + bb.x, 0.f);
  float oy = fmaxf(acc.y * nd + bb.y, 0.f);
  *(float2*)&h1b[(size_t)wid * 128 + lane * 2] = make_float2(ox, oy);
}

// ---------- GEMM2: h2n[n][j] = (sum_k h1b[n][k] W2[k][j]) * norm_src[n] ----------
__global__ __launch_bounds__(256) void k_gemm2(const float* __restrict__ h1b,
                                               const float* __restrict__ W2,
                                               const float* __restrict__ norm_src,
                                               float* __restrict__ h2n, int N) {
  __shared__ float W2l[128 * 8];
  int tid = threadIdx.x;
  for (int i = tid; i < 1024; i += 256) W2l[i] = W2[i];
  __syncthreads();
  int g = blockIdx.x * 256 + tid;
  int node = g >> 3, j = g & 7;
  if (node >= N) return;
  const float* row = h1b + (size_t)node * 128;
  float acc = 0.f;
#pragma unroll
  for (int k = 0; k < 128; k += 4) {
    float4 v = *(const float4*)&row[k];
    acc += v.x * W2l[(k + 0) * 8 + j] + v.y * W2l[(k + 1) * 8 + j] +
           v.z * W2l[(k + 2) * 8 + j] + v.w * W2l[(k + 3) * 8 + j];
  }
  h2n[g] = acc * norm_src[node];
}

// ---------- layer-2 aggregation + graph mean-pool numerator ----------
// 8 lanes per node; result -> atomicAdd into per-graph sums (800 slots).
__global__ __launch_bounds__(256) void k_agg2pool(const float* __restrict__ h2n,
                                                  const int* __restrict__ off,
                                                  const int* __restrict__ esrc,
                                                  const float* __restrict__ norm_dst,
                                                  const float* __restrict__ b2,
                                                  const int* __restrict__ gids,
                                                  float* __restrict__ gsum, int N) {
  int tid = threadIdx.x;
  int g = blockIdx.x * 256 + tid;
  int node = g >> 3, j = g & 7;
  if (node >= N) return;
  int i0 = off[node], i1 = off[node + 1];
  int lane8 = tid & 7;
  float acc = 0.f;
  for (int i = i0; i < i1; i += 8) {
    int cnt = min(8, i1 - i);
    int eid = (i + lane8 < i1) ? esrc[i + lane8] : 0;
    for (int t = 0; t < cnt; ++t) {
      int s = __shfl(eid, t, 8);
      acc += h2n[s * 8 + j];
    }
  }
  float r = acc * norm_dst[node] + b2[j];
  atomicAdd(&gsum[gids[node] * 8 + j], r);
}

// ---------- final: out = gsum / max(count,1) ----------
__global__ void k_final(const float* __restrict__ gsum, const int* __restrict__ gcnt,
                        float* __restrict__ out, int total) {
  int i = blockIdx.x * 256 + threadIdx.x;
  if (i < total) {
    out[i] = gsum[i] / fmaxf((float)gcnt[i >> 3], 1.f);
  }
}

extern "C" void kernel_launch(void* const* d_in, const int* in_sizes, int n_in,
                              void* d_out, int out_size, void* d_ws, size_t ws_size,
                              hipStream_t stream) {
  const float* x  = (const float*)d_in[0];
  const float* W1 = (const float*)d_in[1];
  const float* b1 = (const float*)d_in[2];
  const float* W2 = (const float*)d_in[3];
  const float* b2 = (const float*)d_in[4];
  const int* src  = (const int*)d_in[5];
  const int* dst  = (const int*)d_in[6];
  const int* gids = (const int*)d_in[7];
  int N = in_sizes[0] / F1;
  int E = in_sizes[5];
  int NG = out_size / F2;
  float* out = (float*)d_out;

  // workspace layout (zeroed arrays first -> one memset)
  char* p = (char*)d_ws;
  auto alloc = [&](size_t bytes) -> void* {
    void* r = (void*)p;
    p += (bytes + 255) & ~(size_t)255;
    return r;
  };
  int* deg_out   = (int*)alloc((size_t)N * 4);
  int* deg_in    = (int*)alloc((size_t)N * 4);
  float* gsum    = (float*)alloc((size_t)NG * F2 * 4);
  int* gcnt      = (int*)alloc((size_t)NG * 4);
  size_t zero_bytes = (size_t)((char*)p - (char*)deg_out);
  float* norm_src = (float*)alloc((size_t)N * 4);
  float* norm_dst = (float*)alloc((size_t)N * 4);
  int* off       = (int*)alloc((size_t)(N + 1) * 4);
  int* cursor    = (int*)alloc((size_t)N * 4);
  int* esrc      = (int*)alloc((size_t)E * 4);
  float* h1n     = (float*)alloc((size_t)N * F1 * 4);
  float* h1b     = (float*)alloc((size_t)N * F1 * 4);
  float* h2n     = (float*)alloc((size_t)N * F2 * 4);
  (void)ws_size; (void)n_in;

  hipMemsetAsync(deg_out, 0, zero_bytes, stream);

  k_degrees<<<(E + 255) / 256, 256, 0, stream>>>(src, dst, deg_out, deg_in, E);
  k_norms<<<(N + 255) / 256, 256, 0, stream>>>(deg_out, deg_in, gids, norm_src, norm_dst, gcnt, N);
  k_scan<<<1, 1024, 0, stream>>>(deg_in, off, cursor, N);
  k_bucket<<<(E + 255) / 256, 256, 0, stream>>>(src, dst, cursor, esrc, E);
  k_gemm1<<<dim3((N + 63) / 64, 2), 256, 0, stream>>>(x, W1, norm_src, h1n, N);
  k_agg1<<<(N + 3) / 4, 256, 0, stream>>>(h1n, off, esrc, norm_dst, b1, h1b, N);
  k_gemm2<<<((size_t)N * 8 + 255) / 256, 256, 0, stream>>>(h1b, W2, norm_src, h2n, N);
  k_agg2pool<<<((size_t)N * 8 + 255) / 256, 256, 0, stream>>>(h2n, off, esrc, norm_dst, b2, gids, gsum, N);
  k_final<<<(NG * F2 + 255) / 256, 256, 0, stream>>>(gsum, gcnt, out, NG * F2);
}

// Round 2
// 486.745 us; speedup vs baseline: 1.3002x; 1.3002x over previous
//
#include <hip/hip_runtime.h>

#define F1 128
#define F2 8

// ---------- degree histogram ----------
__global__ void k_degrees(const int* __restrict__ src, const int* __restrict__ dst,
                          int* __restrict__ deg_out, int* __restrict__ deg_in, int E) {
  int e = blockIdx.x * 256 + threadIdx.x;
  if (e < E) {
    atomicAdd(&deg_out[src[e]], 1);
    atomicAdd(&deg_in[dst[e]], 1);
  }
}

// ---------- norms (pure elementwise now — gcnt atomics removed) ----------
__global__ void k_norms(const int* __restrict__ deg_out, const int* __restrict__ deg_in,
                        float* __restrict__ norm_src, float* __restrict__ norm_dst, int N) {
  int n = blockIdx.x * 256 + threadIdx.x;
  if (n < N) {
    int dout = deg_out[n], din = deg_in[n];
    norm_src[n] = dout > 0 ? rsqrtf((float)dout) : 0.f;
    norm_dst[n] = din > 0 ? rsqrtf((float)din) : 0.f;
  }
}

// ---------- single-block exclusive scan of deg_in -> CSR offsets ----------
__global__ __launch_bounds__(1024) void k_scan(const int* __restrict__ deg_in,
                                               int* __restrict__ off, int* __restrict__ cursor,
                                               int N) {
  __shared__ int sums[1024];
  int t = threadIdx.x;
  int chunk = (N + 1023) / 1024;
  int base = t * chunk;
  int s = 0;
  for (int i = 0; i < chunk; ++i) {
    int idx = base + i;
    if (idx < N) s += deg_in[idx];
  }
  sums[t] = s;
  __syncthreads();
  for (int d = 1; d < 1024; d <<= 1) {
    int v = (t >= d) ? sums[t - d] : 0;
    __syncthreads();
    sums[t] += v;
    __syncthreads();
  }
  int run = (t == 0) ? 0 : sums[t - 1];
  for (int i = 0; i < chunk; ++i) {
    int idx = base + i;
    if (idx < N) {
      off[idx] = run;
      cursor[idx] = run;
      run += deg_in[idx];
    }
  }
  if (t == 1023) off[N] = run;
}

// ---------- bucket edges by destination: esrc[p] = src ----------
__global__ void k_bucket(const int* __restrict__ src, const int* __restrict__ dst,
                         int* __restrict__ cursor, int* __restrict__ esrc, int E) {
  int e = blockIdx.x * 256 + threadIdx.x;
  if (e < E) {
    int p = atomicAdd(&cursor[dst[e]], 1);
    esrc[p] = src[e];
  }
}

// ---------- GEMM1: h1n[n][c] = (sum_k x[n][k] W1[k][c]) * norm_src[n] ----------
__global__ __launch_bounds__(256) void k_gemm1(const float* __restrict__ x,
                                               const float* __restrict__ W1,
                                               const float* __restrict__ norm_src,
                                               float* __restrict__ h1n, int N) {
  __shared__ float Wlds[128 * 64];   // [k][cc]
  __shared__ float xsT[128 * 64];    // [k][r]
  int row0 = blockIdx.x * 64;
  int c0 = blockIdx.y * 64;
  int tid = threadIdx.x;

  for (int i = tid; i < 2048; i += 256) {
    int k = i >> 4;
    int cc = (i & 15) << 2;
    *(float4*)&Wlds[k * 64 + cc] = *(const float4*)&W1[k * 128 + c0 + cc];
  }
  for (int i = tid; i < 2048; i += 256) {
    int r = i & 63;
    int kb = (i >> 6) << 2;
    int grow = row0 + r;
    float4 v = make_float4(0.f, 0.f, 0.f, 0.f);
    if (grow < N) v = *(const float4*)&x[(size_t)grow * 128 + kb];
    xsT[(kb + 0) * 64 + r] = v.x;
    xsT[(kb + 1) * 64 + r] = v.y;
    xsT[(kb + 2) * 64 + r] = v.z;
    xsT[(kb + 3) * 64 + r] = v.w;
  }
  __syncthreads();

  int tc = tid & 15;
  int tr = tid >> 4;
  float acc[4][4] = {{0.f}};
#pragma unroll 4
  for (int k = 0; k < 128; ++k) {
    float4 xv = *(const float4*)&xsT[k * 64 + tr * 4];
    float4 wv = *(const float4*)&Wlds[k * 64 + tc * 4];
    acc[0][0] += xv.x * wv.x; acc[0][1] += xv.x * wv.y; acc[0][2] += xv.x * wv.z; acc[0][3] += xv.x * wv.w;
    acc[1][0] += xv.y * wv.x; acc[1][1] += xv.y * wv.y; acc[1][2] += xv.y * wv.z; acc[1][3] += xv.y * wv.w;
    acc[2][0] += xv.z * wv.x; acc[2][1] += xv.z * wv.y; acc[2][2] += xv.z * wv.z; acc[2][3] += xv.z * wv.w;
    acc[3][0] += xv.w * wv.x; acc[3][1] += xv.w * wv.y; acc[3][2] += xv.w * wv.z; acc[3][3] += xv.w * wv.w;
  }
#pragma unroll
  for (int i = 0; i < 4; ++i) {
    int grow = row0 + tr * 4 + i;
    if (grow < N) {
      float ns = norm_src[grow];
      float4 o = make_float4(acc[i][0] * ns, acc[i][1] * ns, acc[i][2] * ns, acc[i][3] * ns);
      *(float4*)&h1n[(size_t)grow * 128 + c0 + tc * 4] = o;
    }
  }
}

// ---------- layer-1 aggregation: one wave per dst node, 2 edges per iteration ----------
// Each 32-lane half-wave reads one full 128-float row as float4; halves combine at end.
__global__ __launch_bounds__(256) void k_agg1(const float* __restrict__ h1n,
                                              const int* __restrict__ off,
                                              const int* __restrict__ esrc,
                                              const float* __restrict__ norm_dst,
                                              const float* __restrict__ b1,
                                              float* __restrict__ h1b, int N) {
  int wid = (blockIdx.x * 256 + threadIdx.x) >> 6;
  int lane = threadIdx.x & 63;
  if (wid >= N) return;
  int i0 = off[wid], i1 = off[wid + 1];
  int half = lane >> 5;      // which edge of the pair
  int fl = lane & 31;        // float4 chunk index within the row
  float4 acc = make_float4(0.f, 0.f, 0.f, 0.f);
  for (int i = i0; i < i1; i += 64) {
    int cnt = min(64, i1 - i);
    int eid = (i + lane < i1) ? esrc[i + lane] : -1;
    for (int t = 0; t < cnt; t += 2) {
      int s = __shfl(eid, t + half);   // half=1 may read the sentinel on odd tails
      if (s >= 0) {
        float4 v = *(const float4*)&h1n[(size_t)s * 128 + fl * 4];
        acc.x += v.x; acc.y += v.y; acc.z += v.z; acc.w += v.w;
      }
    }
  }
  // fold upper half into lower half
  acc.x += __shfl_down(acc.x, 32);
  acc.y += __shfl_down(acc.y, 32);
  acc.z += __shfl_down(acc.z, 32);
  acc.w += __shfl_down(acc.w, 32);
  if (half == 0) {
    float nd = norm_dst[wid];
    float4 bb = *(const float4*)&b1[fl * 4];
    float4 o;
    o.x = fmaxf(acc.x * nd + bb.x, 0.f);
    o.y = fmaxf(acc.y * nd + bb.y, 0.f);
    o.z = fmaxf(acc.z * nd + bb.z, 0.f);
    o.w = fmaxf(acc.w * nd + bb.w, 0.f);
    *(float4*)&h1b[(size_t)wid * 128 + fl * 4] = o;
  }
}

// ---------- GEMM2: h2n[n][j] = (sum_k h1b[n][k] W2[k][j]) * norm_src[n] ----------
__global__ __launch_bounds__(256) void k_gemm2(const float* __restrict__ h1b,
                                               const float* __restrict__ W2,
                                               const float* __restrict__ norm_src,
                                               float* __restrict__ h2n, int N) {
  __shared__ float W2l[128 * 8];
  int tid = threadIdx.x;
  for (int i = tid; i < 1024; i += 256) W2l[i] = W2[i];
  __syncthreads();
  int g = blockIdx.x * 256 + tid;
  int node = g >> 3, j = g & 7;
  if (node >= N) return;
  const float* row = h1b + (size_t)node * 128;
  float acc = 0.f;
#pragma unroll
  for (int k = 0; k < 128; k += 4) {
    float4 v = *(const float4*)&row[k];
    acc += v.x * W2l[(k + 0) * 8 + j] + v.y * W2l[(k + 1) * 8 + j] +
           v.z * W2l[(k + 2) * 8 + j] + v.w * W2l[(k + 3) * 8 + j];
  }
  h2n[g] = acc * norm_src[node];
}

// ---------- layer-2 aggregation + graph mean-pool numerator ----------
__global__ __launch_bounds__(256) void k_agg2pool(const float* __restrict__ h2n,
                                                  const int* __restrict__ off,
                                                  const int* __restrict__ esrc,
                                                  const float* __restrict__ norm_dst,
                                                  const float* __restrict__ b2,
                                                  const int* __restrict__ gids,
                                                  float* __restrict__ gsum, int N) {
  int tid = threadIdx.x;
  int g = blockIdx.x * 256 + tid;
  int node = g >> 3, j = g & 7;
  if (node >= N) return;
  int i0 = off[node], i1 = off[node + 1];
  int lane8 = tid & 7;
  float acc = 0.f;
  for (int i = i0; i < i1; i += 8) {
    int cnt = min(8, i1 - i);
    int eid = (i + lane8 < i1) ? esrc[i + lane8] : 0;
    for (int t = 0; t < cnt; ++t) {
      int s = __shfl(eid, t, 8);
      acc += h2n[s * 8 + j];
    }
  }
  float r = acc * norm_dst[node] + b2[j];
  atomicAdd(&gsum[gids[node] * 8 + j], r);
}

// ---------- final: out = gsum / count, counts via binary search on sorted gids ----------
__global__ void k_final(const float* __restrict__ gsum, const int* __restrict__ gids,
                        float* __restrict__ out, int NG, int N) {
  int i = blockIdx.x * 256 + threadIdx.x;
  if (i < NG * F2) {
    int g = i >> 3;
    int lo = 0, hi = N;
    while (lo < hi) { int m = (lo + hi) >> 1; if (gids[m] < g) lo = m + 1; else hi = m; }
    int lb = lo;
    lo = 0; hi = N;
    while (lo < hi) { int m = (lo + hi) >> 1; if (gids[m] <= g) lo = m + 1; else hi = m; }
    int cnt = lo - lb;
    out[i] = gsum[i] / fmaxf((float)cnt, 1.f);
  }
}

extern "C" void kernel_launch(void* const* d_in, const int* in_sizes, int n_in,
                              void* d_out, int out_size, void* d_ws, size_t ws_size,
                              hipStream_t stream) {
  const float* x  = (const float*)d_in[0];
  const float* W1 = (const float*)d_in[1];
  const float* b1 = (const float*)d_in[2];
  const float* W2 = (const float*)d_in[3];
  const float* b2 = (const float*)d_in[4];
  const int* src  = (const int*)d_in[5];
  const int* dst  = (const int*)d_in[6];
  const int* gids = (const int*)d_in[7];
  int N = in_sizes[0] / F1;
  int E = in_sizes[5];
  int NG = out_size / F2;
  float* out = (float*)d_out;

  char* p = (char*)d_ws;
  auto alloc = [&](size_t bytes) -> void* {
    void* r = (void*)p;
    p += (bytes + 255) & ~(size_t)255;
    return r;
  };
  int* deg_out   = (int*)alloc((size_t)N * 4);
  int* deg_in    = (int*)alloc((size_t)N * 4);
  float* gsum    = (float*)alloc((size_t)NG * F2 * 4);
  size_t zero_bytes = (size_t)((char*)p - (char*)deg_out);
  float* norm_src = (float*)alloc((size_t)N * 4);
  float* norm_dst = (float*)alloc((size_t)N * 4);
  int* off       = (int*)alloc((size_t)(N + 1) * 4);
  int* cursor    = (int*)alloc((size_t)N * 4);
  int* esrc      = (int*)alloc((size_t)E * 4);
  float* h1n     = (float*)alloc((size_t)N * F1 * 4);
  float* h1b     = (float*)alloc((size_t)N * F1 * 4);
  float* h2n     = (float*)alloc((size_t)N * F2 * 4);
  (void)ws_size; (void)n_in;

  hipMemsetAsync(deg_out, 0, zero_bytes, stream);

  k_degrees<<<(E + 255) / 256, 256, 0, stream>>>(src, dst, deg_out, deg_in, E);
  k_norms<<<(N + 255) / 256, 256, 0, stream>>>(deg_out, deg_in, norm_src, norm_dst, N);
  k_scan<<<1, 1024, 0, stream>>>(deg_in, off, cursor, N);
  k_bucket<<<(E + 255) / 256, 256, 0, stream>>>(src, dst, cursor, esrc, E);
  k_gemm1<<<dim3((N + 63) / 64, 2), 256, 0, stream>>>(x, W1, norm_src, h1n, N);
  k_agg1<<<(N + 3) / 4, 256, 0, stream>>>(h1n, off, esrc, norm_dst, b1, h1b, N);
  k_gemm2<<<((size_t)N * 8 + 255) / 256, 256, 0, stream>>>(h1b, W2, norm_src, h2n, N);
  k_agg2pool<<<((size_t)N * 8 + 255) / 256, 256, 0, stream>>>(h2n, off, esrc, norm_dst, b2, gids, gsum, N);
  k_final<<<(NG * F2 + 255) / 256, 256, 0, stream>>>(gsum, gids, out, NG, N);
}

// Round 3
// 367.747 us; speedup vs baseline: 1.7209x; 1.3236x over previous
//
#include <hip/hip_runtime.h>

#define F1 128
#define F2 8
#define SCAN_CHUNK 1024  // elements per block in the 3-phase scan

// ---------- degree histogram ----------
__global__ void k_degrees(const int* __restrict__ src, const int* __restrict__ dst,
                          int* __restrict__ deg_out, int* __restrict__ deg_in, int E) {
  int e = blockIdx.x * 256 + threadIdx.x;
  if (e < E) {
    atomicAdd(&deg_out[src[e]], 1);
    atomicAdd(&deg_in[dst[e]], 1);
  }
}

// ---------- norms (pure elementwise) ----------
__global__ void k_norms(const int* __restrict__ deg_out, const int* __restrict__ deg_in,
                        float* __restrict__ norm_src, float* __restrict__ norm_dst, int N) {
  int n = blockIdx.x * 256 + threadIdx.x;
  if (n < N) {
    int dout = deg_out[n], din = deg_in[n];
    norm_src[n] = dout > 0 ? rsqrtf((float)dout) : 0.f;
    norm_dst[n] = din > 0 ? rsqrtf((float)din) : 0.f;
  }
}

// ---------- 3-phase parallel scan ----------
// phase 1: per-block sums of 1024-element chunks
__global__ __launch_bounds__(256) void k_scan1(const int* __restrict__ deg_in,
                                               int* __restrict__ partial, int N) {
  __shared__ int red[256];
  int t = threadIdx.x;
  int base = blockIdx.x * SCAN_CHUNK + t * 4;
  int s = 0;
#pragma unroll
  for (int i = 0; i < 4; ++i) {
    int idx = base + i;
    if (idx < N) s += deg_in[idx];
  }
  red[t] = s;
  __syncthreads();
  for (int d = 128; d > 0; d >>= 1) {
    if (t < d) red[t] += red[t + d];
    __syncthreads();
  }
  if (t == 0) partial[blockIdx.x] = red[0];
}

// phase 2: single block exclusive-scans the partials (B <= 1024)
__global__ __launch_bounds__(1024) void k_scan2(int* __restrict__ partial, int B) {
  __shared__ int s[1024];
  int t = threadIdx.x;
  s[t] = (t < B) ? partial[t] : 0;
  __syncthreads();
  for (int d = 1; d < 1024; d <<= 1) {
    int v = (t >= d) ? s[t - d] : 0;
    __syncthreads();
    s[t] += v;
    __syncthreads();
  }
  if (t < B) partial[t] = (t == 0) ? 0 : s[t - 1];
}

// phase 3: block-local exclusive scan + block offset -> off, cursor
__global__ __launch_bounds__(256) void k_scan3(const int* __restrict__ deg_in,
                                               const int* __restrict__ partial,
                                               int* __restrict__ off, int* __restrict__ cursor,
                                               int N) {
  __shared__ int red[256];
  int t = threadIdx.x;
  int base = blockIdx.x * SCAN_CHUNK + t * 4;
  int v[4];
  int s = 0;
#pragma unroll
  for (int i = 0; i < 4; ++i) {
    int idx = base + i;
    v[i] = (idx < N) ? deg_in[idx] : 0;
    s += v[i];
  }
  red[t] = s;
  __syncthreads();
  int own = s;
  for (int d = 1; d < 256; d <<= 1) {
    int u = (t >= d) ? red[t - d] : 0;
    __syncthreads();
    red[t] += u;
    __syncthreads();
  }
  int excl = red[t] - own + partial[blockIdx.x];
#pragma unroll
  for (int i = 0; i < 4; ++i) {
    int idx = base + i;
    if (idx < N) {
      off[idx] = excl;
      cursor[idx] = excl;
      excl += v[i];
      if (idx == N - 1) off[N] = excl;  // total edge count
    }
  }
}

// ---------- bucket edges by destination: esrc[p] = src ----------
__global__ void k_bucket(const int* __restrict__ src, const int* __restrict__ dst,
                         int* __restrict__ cursor, int* __restrict__ esrc, int E) {
  int e = blockIdx.x * 256 + threadIdx.x;
  if (e < E) {
    int p = atomicAdd(&cursor[dst[e]], 1);
    esrc[p] = src[e];
  }
}

// ---------- GEMM1: h1n[n][c] = (sum_k x[n][k] W1[k][c]) * norm_src[n] ----------
__global__ __launch_bounds__(256) void k_gemm1(const float* __restrict__ x,
                                               const float* __restrict__ W1,
                                               const float* __restrict__ norm_src,
                                               float* __restrict__ h1n, int N) {
  __shared__ float Wlds[128 * 64];   // [k][cc]
  __shared__ float xsT[128 * 64];    // [k][r]
  int row0 = blockIdx.x * 64;
  int c0 = blockIdx.y * 64;
  int tid = threadIdx.x;

  for (int i = tid; i < 2048; i += 256) {
    int k = i >> 4;
    int cc = (i & 15) << 2;
    *(float4*)&Wlds[k * 64 + cc] = *(const float4*)&W1[k * 128 + c0 + cc];
  }
  for (int i = tid; i < 2048; i += 256) {
    int r = i & 63;
    int kb = (i >> 6) << 2;
    int grow = row0 + r;
    float4 v = make_float4(0.f, 0.f, 0.f, 0.f);
    if (grow < N) v = *(const float4*)&x[(size_t)grow * 128 + kb];
    xsT[(kb + 0) * 64 + r] = v.x;
    xsT[(kb + 1) * 64 + r] = v.y;
    xsT[(kb + 2) * 64 + r] = v.z;
    xsT[(kb + 3) * 64 + r] = v.w;
  }
  __syncthreads();

  int tc = tid & 15;
  int tr = tid >> 4;
  float acc[4][4] = {{0.f}};
#pragma unroll 4
  for (int k = 0; k < 128; ++k) {
    float4 xv = *(const float4*)&xsT[k * 64 + tr * 4];
    float4 wv = *(const float4*)&Wlds[k * 64 + tc * 4];
    acc[0][0] += xv.x * wv.x; acc[0][1] += xv.x * wv.y; acc[0][2] += xv.x * wv.z; acc[0][3] += xv.x * wv.w;
    acc[1][0] += xv.y * wv.x; acc[1][1] += xv.y * wv.y; acc[1][2] += xv.y * wv.z; acc[1][3] += xv.y * wv.w;
    acc[2][0] += xv.z * wv.x; acc[2][1] += xv.z * wv.y; acc[2][2] += xv.z * wv.z; acc[2][3] += xv.z * wv.w;
    acc[3][0] += xv.w * wv.x; acc[3][1] += xv.w * wv.y; acc[3][2] += xv.w * wv.z; acc[3][3] += xv.w * wv.w;
  }
#pragma unroll
  for (int i = 0; i < 4; ++i) {
    int grow = row0 + tr * 4 + i;
    if (grow < N) {
      float ns = norm_src[grow];
      float4 o = make_float4(acc[i][0] * ns, acc[i][1] * ns, acc[i][2] * ns, acc[i][3] * ns);
      *(float4*)&h1n[(size_t)grow * 128 + c0 + tc * 4] = o;
    }
  }
}

// ---------- layer-1 aggregation: one wave per dst node, 2 edges per iteration ----------
__global__ __launch_bounds__(256) void k_agg1(const float* __restrict__ h1n,
                                              const int* __restrict__ off,
                                              const int* __restrict__ esrc,
                                              const float* __restrict__ norm_dst,
                                              const float* __restrict__ b1,
                                              float* __restrict__ h1b, int N) {
  int wid = (blockIdx.x * 256 + threadIdx.x) >> 6;
  int lane = threadIdx.x & 63;
  if (wid >= N) return;
  int i0 = off[wid], i1 = off[wid + 1];
  int half = lane >> 5;
  int fl = lane & 31;
  float4 acc = make_float4(0.f, 0.f, 0.f, 0.f);
  for (int i = i0; i < i1; i += 64) {
    int cnt = min(64, i1 - i);
    int eid = (i + lane < i1) ? esrc[i + lane] : -1;
    for (int t = 0; t < cnt; t += 2) {
      int s = __shfl(eid, t + half);
      if (s >= 0) {
        float4 v = *(const float4*)&h1n[(size_t)s * 128 + fl * 4];
        acc.x += v.x; acc.y += v.y; acc.z += v.z; acc.w += v.w;
      }
    }
  }
  acc.x += __shfl_down(acc.x, 32);
  acc.y += __shfl_down(acc.y, 32);
  acc.z += __shfl_down(acc.z, 32);
  acc.w += __shfl_down(acc.w, 32);
  if (half == 0) {
    float nd = norm_dst[wid];
    float4 bb = *(const float4*)&b1[fl * 4];
    float4 o;
    o.x = fmaxf(acc.x * nd + bb.x, 0.f);
    o.y = fmaxf(acc.y * nd + bb.y, 0.f);
    o.z = fmaxf(acc.z * nd + bb.z, 0.f);
    o.w = fmaxf(acc.w * nd + bb.w, 0.f);
    *(float4*)&h1b[(size_t)wid * 128 + fl * 4] = o;
  }
}

// ---------- GEMM2: h2n[n][j] = (sum_k h1b[n][k] W2[k][j]) * norm_src[n] ----------
__global__ __launch_bounds__(256) void k_gemm2(const float* __restrict__ h1b,
                                               const float* __restrict__ W2,
                                               const float* __restrict__ norm_src,
                                               float* __restrict__ h2n, int N) {
  __shared__ float W2l[128 * 8];
  int tid = threadIdx.x;
  for (int i = tid; i < 1024; i += 256) W2l[i] = W2[i];
  __syncthreads();
  int g = blockIdx.x * 256 + tid;
  int node = g >> 3, j = g & 7;
  if (node >= N) return;
  const float* row = h1b + (size_t)node * 128;
  float acc = 0.f;
#pragma unroll
  for (int k = 0; k < 128; k += 4) {
    float4 v = *(const float4*)&row[k];
    acc += v.x * W2l[(k + 0) * 8 + j] + v.y * W2l[(k + 1) * 8 + j] +
           v.z * W2l[(k + 2) * 8 + j] + v.w * W2l[(k + 3) * 8 + j];
  }
  h2n[g] = acc * norm_src[node];
}

// ---------- layer-2 aggregation + graph mean-pool numerator ----------
__global__ __launch_bounds__(256) void k_agg2pool(const float* __restrict__ h2n,
                                                  const int* __restrict__ off,
                                                  const int* __restrict__ esrc,
                                                  const float* __restrict__ norm_dst,
                                                  const float* __restrict__ b2,
                                                  const int* __restrict__ gids,
                                                  float* __restrict__ gsum, int N) {
  int tid = threadIdx.x;
  int g = blockIdx.x * 256 + tid;
  int node = g >> 3, j = g & 7;
  if (node >= N) return;
  int i0 = off[node], i1 = off[node + 1];
  int lane8 = tid & 7;
  float acc = 0.f;
  for (int i = i0; i < i1; i += 8) {
    int cnt = min(8, i1 - i);
    int eid = (i + lane8 < i1) ? esrc[i + lane8] : 0;
    for (int t = 0; t < cnt; ++t) {
      int s = __shfl(eid, t, 8);
      acc += h2n[s * 8 + j];
    }
  }
  float r = acc * norm_dst[node] + b2[j];
  atomicAdd(&gsum[gids[node] * 8 + j], r);
}

// ---------- final: out = gsum / count, counts via binary search on sorted gids ----------
__global__ void k_final(const float* __restrict__ gsum, const int* __restrict__ gids,
                        float* __restrict__ out, int NG, int N) {
  int i = blockIdx.x * 256 + threadIdx.x;
  if (i < NG * F2) {
    int g = i >> 3;
    int lo = 0, hi = N;
    while (lo < hi) { int m = (lo + hi) >> 1; if (gids[m] < g) lo = m + 1; else hi = m; }
    int lb = lo;
    lo = 0; hi = N;
    while (lo < hi) { int m = (lo + hi) >> 1; if (gids[m] <= g) lo = m + 1; else hi = m; }
    int cnt = lo - lb;
    out[i] = gsum[i] / fmaxf((float)cnt, 1.f);
  }
}

extern "C" void kernel_launch(void* const* d_in, const int* in_sizes, int n_in,
                              void* d_out, int out_size, void* d_ws, size_t ws_size,
                              hipStream_t stream) {
  const float* x  = (const float*)d_in[0];
  const float* W1 = (const float*)d_in[1];
  const float* b1 = (const float*)d_in[2];
  const float* W2 = (const float*)d_in[3];
  const float* b2 = (const float*)d_in[4];
  const int* src  = (const int*)d_in[5];
  const int* dst  = (const int*)d_in[6];
  const int* gids = (const int*)d_in[7];
  int N = in_sizes[0] / F1;
  int E = in_sizes[5];
  int NG = out_size / F2;
  float* out = (float*)d_out;

  char* p = (char*)d_ws;
  auto alloc = [&](size_t bytes) -> void* {
    void* r = (void*)p;
    p += (bytes + 255) & ~(size_t)255;
    return r;
  };
  int* deg_out   = (int*)alloc((size_t)N * 4);
  int* deg_in    = (int*)alloc((size_t)N * 4);
  float* gsum    = (float*)alloc((size_t)NG * F2 * 4);
  size_t zero_bytes = (size_t)((char*)p - (char*)deg_out);
  float* norm_src = (float*)alloc((size_t)N * 4);
  float* norm_dst = (float*)alloc((size_t)N * 4);
  int* off       = (int*)alloc((size_t)(N + 1) * 4);
  int* cursor    = (int*)alloc((size_t)N * 4);
  int* esrc      = (int*)alloc((size_t)E * 4);
  int* partial   = (int*)alloc((size_t)1024 * 4);
  float* h1n     = (float*)alloc((size_t)N * F1 * 4);
  float* h1b     = (float*)alloc((size_t)N * F1 * 4);
  float* h2n     = (float*)alloc((size_t)N * F2 * 4);
  (void)ws_size; (void)n_in;

  hipMemsetAsync(deg_out, 0, zero_bytes, stream);

  int B = (N + SCAN_CHUNK - 1) / SCAN_CHUNK;
  k_degrees<<<(E + 255) / 256, 256, 0, stream>>>(src, dst, deg_out, deg_in, E);
  k_norms<<<(N + 255) / 256, 256, 0, stream>>>(deg_out, deg_in, norm_src, norm_dst, N);
  k_scan1<<<B, 256, 0, stream>>>(deg_in, partial, N);
  k_scan2<<<1, 1024, 0, stream>>>(partial, B);
  k_scan3<<<B, 256, 0, stream>>>(deg_in, partial, off, cursor, N);
  k_bucket<<<(E + 255) / 256, 256, 0, stream>>>(src, dst, cursor, esrc, E);
  k_gemm1<<<dim3((N + 63) / 64, 2), 256, 0, stream>>>(x, W1, norm_src, h1n, N);
  k_agg1<<<(N + 3) / 4, 256, 0, stream>>>(h1n, off, esrc, norm_dst, b1, h1b, N);
  k_gemm2<<<((size_t)N * 8 + 255) / 256, 256, 0, stream>>>(h1b, W2, norm_src, h2n, N);
  k_agg2pool<<<((size_t)N * 8 + 255) / 256, 256, 0, stream>>>(h2n, off, esrc, norm_dst, b2, gids, gsum, N);
  k_final<<<(NG * F2 + 255) / 256, 256, 0, stream>>>(gsum, gids, out, NG, N);
}

// Round 4
// 351.352 us; speedup vs baseline: 1.8012x; 1.0467x over previous
//
#include <hip/hip_runtime.h>

#define F1 128
#define F2 8
#define SCAN_CHUNK 1024
#define NREP 8   // one histogram/cursor replica per XCD (blockIdx & 7 heuristic)

typedef unsigned short us8 __attribute__((ext_vector_type(8)));

__device__ inline unsigned short f2bf(float f) {
  unsigned u = __float_as_uint(f);
  u += 0x7FFF + ((u >> 16) & 1);   // round-to-nearest-even
  return (unsigned short)(u >> 16);
}
__device__ inline float bf2f(unsigned short h) {
  return __uint_as_float(((unsigned)h) << 16);
}

// ---------- degree histograms, 8 XCD-local replicas ----------
__global__ void k_degrees(const int* __restrict__ src, const int* __restrict__ dst,
                          int* __restrict__ deg_out_r, int* __restrict__ deg_in_r,
                          int E, int Ns) {
  int e = blockIdx.x * 256 + threadIdx.x;
  int rep = blockIdx.x & (NREP - 1);
  if (e < E) {
    atomicAdd(&deg_out_r[rep * Ns + src[e]], 1);
    atomicAdd(&deg_in_r[rep * Ns + dst[e]], 1);
  }
}

// ---------- reduce replicas -> deg_in (for scan) + norms ----------
__global__ void k_norms(const int* __restrict__ deg_out_r, const int* __restrict__ deg_in_r,
                        float* __restrict__ norm_src, float* __restrict__ norm_dst,
                        int* __restrict__ deg_in, int N, int Ns) {
  int n = blockIdx.x * 256 + threadIdx.x;
  if (n < N) {
    int dout = 0, din = 0;
#pragma unroll
    for (int r = 0; r < NREP; ++r) {
      dout += deg_out_r[r * Ns + n];
      din  += deg_in_r[r * Ns + n];
    }
    deg_in[n] = din;
    norm_src[n] = dout > 0 ? rsqrtf((float)dout) : 0.f;
    norm_dst[n] = din > 0 ? rsqrtf((float)din) : 0.f;
  }
}

// ---------- 3-phase parallel scan of deg_in -> off ----------
__global__ __launch_bounds__(256) void k_scan1(const int* __restrict__ deg_in,
                                               int* __restrict__ partial, int N) {
  __shared__ int red[256];
  int t = threadIdx.x;
  int base = blockIdx.x * SCAN_CHUNK + t * 4;
  int s = 0;
#pragma unroll
  for (int i = 0; i < 4; ++i) {
    int idx = base + i;
    if (idx < N) s += deg_in[idx];
  }
  red[t] = s;
  __syncthreads();
  for (int d = 128; d > 0; d >>= 1) {
    if (t < d) red[t] += red[t + d];
    __syncthreads();
  }
  if (t == 0) partial[blockIdx.x] = red[0];
}

__global__ __launch_bounds__(1024) void k_scan2(int* __restrict__ partial, int B) {
  __shared__ int s[1024];
  int t = threadIdx.x;
  s[t] = (t < B) ? partial[t] : 0;
  __syncthreads();
  for (int d = 1; d < 1024; d <<= 1) {
    int v = (t >= d) ? s[t - d] : 0;
    __syncthreads();
    s[t] += v;
    __syncthreads();
  }
  if (t < B) partial[t] = (t == 0) ? 0 : s[t - 1];
}

__global__ __launch_bounds__(256) void k_scan3(const int* __restrict__ deg_in,
                                               const int* __restrict__ partial,
                                               int* __restrict__ off, int N) {
  __shared__ int red[256];
  int t = threadIdx.x;
  int base = blockIdx.x * SCAN_CHUNK + t * 4;
  int v[4];
  int s = 0;
#pragma unroll
  for (int i = 0; i < 4; ++i) {
    int idx = base + i;
    v[i] = (idx < N) ? deg_in[idx] : 0;
    s += v[i];
  }
  red[t] = s;
  __syncthreads();
  int own = s;
  for (int d = 1; d < 256; d <<= 1) {
    int u = (t >= d) ? red[t - d] : 0;
    __syncthreads();
    red[t] += u;
    __syncthreads();
  }
  int excl = red[t] - own + partial[blockIdx.x];
#pragma unroll
  for (int i = 0; i < 4; ++i) {
    int idx = base + i;
    if (idx < N) {
      off[idx] = excl;
      excl += v[i];
      if (idx == N - 1) off[N] = excl;
    }
  }
}

// ---------- seed per-replica cursors: cursor_r[r][n] = off[n] + sum_{r'<r} deg_in_r[r'][n] ----------
__global__ void k_cursors(const int* __restrict__ off, const int* __restrict__ deg_in_r,
                          int* __restrict__ cursor_r, int N, int Ns) {
  int n = blockIdx.x * 256 + threadIdx.x;
  if (n < N) {
    int run = off[n];
#pragma unroll
    for (int r = 0; r < NREP; ++r) {
      cursor_r[r * Ns + n] = run;
      run += deg_in_r[r * Ns + n];
    }
  }
}

// ---------- bucket edges by destination (XCD-local cursor atomics) ----------
__global__ void k_bucket(const int* __restrict__ src, const int* __restrict__ dst,
                         int* __restrict__ cursor_r, int* __restrict__ esrc, int E, int Ns) {
  int e = blockIdx.x * 256 + threadIdx.x;
  int rep = blockIdx.x & (NREP - 1);
  if (e < E) {
    int p = atomicAdd(&cursor_r[rep * Ns + dst[e]], 1);
    esrc[p] = src[e];
  }
}

// ---------- GEMM1: h1n[n][c] = bf16( (sum_k x[n][k] W1[k][c]) * norm_src[n] ) ----------
__global__ __launch_bounds__(256) void k_gemm1(const float* __restrict__ x,
                                               const float* __restrict__ W1,
                                               const float* __restrict__ norm_src,
                                               unsigned short* __restrict__ h1n, int N) {
  __shared__ float Wlds[128 * 64];   // [k][cc]
  __shared__ float xsT[128 * 64];    // [k][r]
  int row0 = blockIdx.x * 64;
  int c0 = blockIdx.y * 64;
  int tid = threadIdx.x;

  for (int i = tid; i < 2048; i += 256) {
    int k = i >> 4;
    int cc = (i & 15) << 2;
    *(float4*)&Wlds[k * 64 + cc] = *(const float4*)&W1[k * 128 + c0 + cc];
  }
  for (int i = tid; i < 2048; i += 256) {
    int r = i & 63;
    int kb = (i >> 6) << 2;
    int grow = row0 + r;
    float4 v = make_float4(0.f, 0.f, 0.f, 0.f);
    if (grow < N) v = *(const float4*)&x[(size_t)grow * 128 + kb];
    xsT[(kb + 0) * 64 + r] = v.x;
    xsT[(kb + 1) * 64 + r] = v.y;
    xsT[(kb + 2) * 64 + r] = v.z;
    xsT[(kb + 3) * 64 + r] = v.w;
  }
  __syncthreads();

  int tc = tid & 15;
  int tr = tid >> 4;
  float acc[4][4] = {{0.f}};
#pragma unroll 4
  for (int k = 0; k < 128; ++k) {
    float4 xv = *(const float4*)&xsT[k * 64 + tr * 4];
    float4 wv = *(const float4*)&Wlds[k * 64 + tc * 4];
    acc[0][0] += xv.x * wv.x; acc[0][1] += xv.x * wv.y; acc[0][2] += xv.x * wv.z; acc[0][3] += xv.x * wv.w;
    acc[1][0] += xv.y * wv.x; acc[1][1] += xv.y * wv.y; acc[1][2] += xv.y * wv.z; acc[1][3] += xv.y * wv.w;
    acc[2][0] += xv.z * wv.x; acc[2][1] += xv.z * wv.y; acc[2][2] += xv.z * wv.z; acc[2][3] += xv.z * wv.w;
    acc[3][0] += xv.w * wv.x; acc[3][1] += xv.w * wv.y; acc[3][2] += xv.w * wv.z; acc[3][3] += xv.w * wv.w;
  }
#pragma unroll
  for (int i = 0; i < 4; ++i) {
    int grow = row0 + tr * 4 + i;
    if (grow < N) {
      float ns = norm_src[grow];
      ushort4 o;
      o.x = f2bf(acc[i][0] * ns);
      o.y = f2bf(acc[i][1] * ns);
      o.z = f2bf(acc[i][2] * ns);
      o.w = f2bf(acc[i][3] * ns);
      *(ushort4*)&h1n[(size_t)grow * 128 + c0 + tc * 4] = o;
    }
  }
}

// ---------- layer-1 aggregation: one wave per dst node, 4 edges in flight ----------
// 16 lanes per edge-row; each lane loads 8 bf16 (16 B); fp32 accumulate.
__global__ __launch_bounds__(256) void k_agg1(const unsigned short* __restrict__ h1n,
                                              const int* __restrict__ off,
                                              const int* __restrict__ esrc,
                                              const float* __restrict__ norm_dst,
                                              const float* __restrict__ b1,
                                              float* __restrict__ h1b, int N) {
  int wid = (blockIdx.x * 256 + threadIdx.x) >> 6;
  int lane = threadIdx.x & 63;
  if (wid >= N) return;
  int i0 = off[wid], i1 = off[wid + 1];
  int q = lane >> 4;    // which edge of the quad
  int fl = lane & 15;   // 8-feature chunk within the row
  float acc[8] = {0.f, 0.f, 0.f, 0.f, 0.f, 0.f, 0.f, 0.f};
  for (int i = i0; i < i1; i += 64) {
    int cnt = min(64, i1 - i);
    int eid = (i + lane < i1) ? esrc[i + lane] : -1;
    for (int t = 0; t < cnt; t += 4) {
      int s = __shfl(eid, t + q);
      if (s >= 0) {
        us8 v = *(const us8*)&h1n[(size_t)s * 128 + fl * 8];
#pragma unroll
        for (int j = 0; j < 8; ++j) acc[j] += bf2f(v[j]);
      }
    }
  }
#pragma unroll
  for (int j = 0; j < 8; ++j) acc[j] += __shfl_down(acc[j], 32);
#pragma unroll
  for (int j = 0; j < 8; ++j) acc[j] += __shfl_down(acc[j], 16);
  if (lane < 16) {
    float nd = norm_dst[wid];
    float4 b0 = *(const float4*)&b1[fl * 8];
    float4 b4 = *(const float4*)&b1[fl * 8 + 4];
    float4 o0, o4;
    o0.x = fmaxf(acc[0] * nd + b0.x, 0.f);
    o0.y = fmaxf(acc[1] * nd + b0.y, 0.f);
    o0.z = fmaxf(acc[2] * nd + b0.z, 0.f);
    o0.w = fmaxf(acc[3] * nd + b0.w, 0.f);
    o4.x = fmaxf(acc[4] * nd + b4.x, 0.f);
    o4.y = fmaxf(acc[5] * nd + b4.y, 0.f);
    o4.z = fmaxf(acc[6] * nd + b4.z, 0.f);
    o4.w = fmaxf(acc[7] * nd + b4.w, 0.f);
    *(float4*)&h1b[(size_t)wid * 128 + fl * 8] = o0;
    *(float4*)&h1b[(size_t)wid * 128 + fl * 8 + 4] = o4;
  }
}

// ---------- GEMM2: h2n[n][j] = (sum_k h1b[n][k] W2[k][j]) * norm_src[n] ----------
__global__ __launch_bounds__(256) void k_gemm2(const float* __restrict__ h1b,
                                               const float* __restrict__ W2,
                                               const float* __restrict__ norm_src,
                                               float* __restrict__ h2n, int N) {
  __shared__ float W2l[128 * 8];
  int tid = threadIdx.x;
  for (int i = tid; i < 1024; i += 256) W2l[i] = W2[i];
  __syncthreads();
  int g = blockIdx.x * 256 + tid;
  int node = g >> 3, j = g & 7;
  if (node >= N) return;
  const float* row = h1b + (size_t)node * 128;
  float acc = 0.f;
#pragma unroll
  for (int k = 0; k < 128; k += 4) {
    float4 v = *(const float4*)&row[k];
    acc += v.x * W2l[(k + 0) * 8 + j] + v.y * W2l[(k + 1) * 8 + j] +
           v.z * W2l[(k + 2) * 8 + j] + v.w * W2l[(k + 3) * 8 + j];
  }
  h2n[g] = acc * norm_src[node];
}

// ---------- layer-2 aggregation + graph mean-pool numerator ----------
__global__ __launch_bounds__(256) void k_agg2pool(const float* __restrict__ h2n,
                                                  const int* __restrict__ off,
                                                  const int* __restrict__ esrc,
                                                  const float* __restrict__ norm_dst,
                                                  const float* __restrict__ b2,
                                                  const int* __restrict__ gids,
                                                  float* __restrict__ gsum, int N) {
  int tid = threadIdx.x;
  int g = blockIdx.x * 256 + tid;
  int node = g >> 3, j = g & 7;
  if (node >= N) return;
  int i0 = off[node], i1 = off[node + 1];
  int lane8 = tid & 7;
  float acc = 0.f;
  for (int i = i0; i < i1; i += 8) {
    int cnt = min(8, i1 - i);
    int eid = (i + lane8 < i1) ? esrc[i + lane8] : 0;
    for (int t = 0; t < cnt; ++t) {
      int s = __shfl(eid, t, 8);
      acc += h2n[s * 8 + j];
    }
  }
  float r = acc * norm_dst[node] + b2[j];
  atomicAdd(&gsum[gids[node] * 8 + j], r);
}

// ---------- final: out = gsum / count, counts via binary search on sorted gids ----------
__global__ void k_final(const float* __restrict__ gsum, const int* __restrict__ gids,
                        float* __restrict__ out, int NG, int N) {
  int i = blockIdx.x * 256 + threadIdx.x;
  if (i < NG * F2) {
    int g = i >> 3;
    int lo = 0, hi = N;
    while (lo < hi) { int m = (lo + hi) >> 1; if (gids[m] < g) lo = m + 1; else hi = m; }
    int lb = lo;
    lo = 0; hi = N;
    while (lo < hi) { int m = (lo + hi) >> 1; if (gids[m] <= g) lo = m + 1; else hi = m; }
    int cnt = lo - lb;
    out[i] = gsum[i] / fmaxf((float)cnt, 1.f);
  }
}

extern "C" void kernel_launch(void* const* d_in, const int* in_sizes, int n_in,
                              void* d_out, int out_size, void* d_ws, size_t ws_size,
                              hipStream_t stream) {
  const float* x  = (const float*)d_in[0];
  const float* W1 = (const float*)d_in[1];
  const float* b1 = (const float*)d_in[2];
  const float* W2 = (const float*)d_in[3];
  const float* b2 = (const float*)d_in[4];
  const int* src  = (const int*)d_in[5];
  const int* dst  = (const int*)d_in[6];
  const int* gids = (const int*)d_in[7];
  int N = in_sizes[0] / F1;
  int E = in_sizes[5];
  int NG = out_size / F2;
  float* out = (float*)d_out;
  int Ns = (N + 63) & ~63;   // replica stride (64-int aligned)

  char* p = (char*)d_ws;
  auto alloc = [&](size_t bytes) -> void* {
    void* r = (void*)p;
    p += (bytes + 255) & ~(size_t)255;
    return r;
  };
  // zeroed region first
  int* deg_out_r = (int*)alloc((size_t)NREP * Ns * 4);
  int* deg_in_r  = (int*)alloc((size_t)NREP * Ns * 4);
  float* gsum    = (float*)alloc((size_t)NG * F2 * 4);
  size_t zero_bytes = (size_t)((char*)p - (char*)deg_out_r);
  int* deg_in    = (int*)alloc((size_t)N * 4);
  float* norm_src = (float*)alloc((size_t)N * 4);
  float* norm_dst = (float*)alloc((size_t)N * 4);
  int* off       = (int*)alloc((size_t)(N + 1) * 4);
  int* cursor_r  = (int*)alloc((size_t)NREP * Ns * 4);
  int* esrc      = (int*)alloc((size_t)E * 4);
  int* partial   = (int*)alloc((size_t)1024 * 4);
  unsigned short* h1n = (unsigned short*)alloc((size_t)N * F1 * 2);
  float* h1b     = (float*)alloc((size_t)N * F1 * 4);
  float* h2n     = (float*)alloc((size_t)N * F2 * 4);
  (void)ws_size; (void)n_in;

  hipMemsetAsync(deg_out_r, 0, zero_bytes, stream);

  int B = (N + SCAN_CHUNK - 1) / SCAN_CHUNK;
  k_degrees<<<(E + 255) / 256, 256, 0, stream>>>(src, dst, deg_out_r, deg_in_r, E, Ns);
  k_norms<<<(N + 255) / 256, 256, 0, stream>>>(deg_out_r, deg_in_r, norm_src, norm_dst, deg_in, N, Ns);
  k_scan1<<<B, 256, 0, stream>>>(deg_in, partial, N);
  k_scan2<<<1, 1024, 0, stream>>>(partial, B);
  k_scan3<<<B, 256, 0, stream>>>(deg_in, partial, off, N);
  k_cursors<<<(N + 255) / 256, 256, 0, stream>>>(off, deg_in_r, cursor_r, N, Ns);
  k_bucket<<<(E + 255) / 256, 256, 0, stream>>>(src, dst, cursor_r, esrc, E, Ns);
  k_gemm1<<<dim3((N + 63) / 64, 2), 256, 0, stream>>>(x, W1, norm_src, h1n, N);
  k_agg1<<<(N + 3) / 4, 256, 0, stream>>>(h1n, off, esrc, norm_dst, b1, h1b, N);
  k_gemm2<<<((size_t)N * 8 + 255) / 256, 256, 0, stream>>>(h1b, W2, norm_src, h2n, N);
  k_agg2pool<<<((size_t)N * 8 + 255) / 256, 256, 0, stream>>>(h2n, off, esrc, norm_dst, b2, gids, gsum, N);
  k_final<<<(NG * F2 + 255) / 256, 256, 0, stream>>>(gsum, gids, out, NG, N);
}

// Round 5
// 296.641 us; speedup vs baseline: 2.1334x; 1.1844x over previous
//
#include <hip/hip_runtime.h>

#define F1 128
#define F2 8
#define SCAN_CHUNK 1024
#define NREP 8   // one histogram replica per XCD, selected by HW XCC_ID

typedef unsigned short us8 __attribute__((ext_vector_type(8)));

__device__ inline unsigned short f2bf(float f) {
  unsigned u = __float_as_uint(f);
  u += 0x7FFF + ((u >> 16) & 1);   // round-to-nearest-even
  return (unsigned short)(u >> 16);
}
__device__ inline float bf2f(unsigned short h) {
  return __uint_as_float(((unsigned)h) << 16);
}
__device__ inline int xcc_id() {
  unsigned x;
  asm("s_getreg_b32 %0, hwreg(20, 0, 32)" : "=s"(x));  // HW_REG_XCC_ID (gfx940+)
  return (int)(x & (NREP - 1));
}

// ---------- degree histograms: XCD-local L2 atomics into per-XCC replicas ----------
// Counts are mapping-independent (any wave adds to the replica of the XCD it runs
// on); atomicity per replica is physical (one L2 services all updates to it).
__global__ void k_degrees(const int* __restrict__ src, const int* __restrict__ dst,
                          int* __restrict__ deg_out_r, int* __restrict__ deg_in_r,
                          int E, int Ns) {
  int e = blockIdx.x * 256 + threadIdx.x;
  int rep = xcc_id();
  if (e < E) {
    __hip_atomic_fetch_add(&deg_out_r[rep * Ns + src[e]], 1,
                           __ATOMIC_RELAXED, __HIP_MEMORY_SCOPE_WORKGROUP);
    __hip_atomic_fetch_add(&deg_in_r[rep * Ns + dst[e]], 1,
                           __ATOMIC_RELAXED, __HIP_MEMORY_SCOPE_WORKGROUP);
  }
}

// ---------- reduce replicas -> deg_in + norms ----------
__global__ void k_norms(const int* __restrict__ deg_out_r, const int* __restrict__ deg_in_r,
                        float* __restrict__ norm_src, float* __restrict__ norm_dst,
                        int* __restrict__ deg_in, int N, int Ns) {
  int n = blockIdx.x * 256 + threadIdx.x;
  if (n < N) {
    int dout = 0, din = 0;
#pragma unroll
    for (int r = 0; r < NREP; ++r) {
      dout += deg_out_r[r * Ns + n];
      din  += deg_in_r[r * Ns + n];
    }
    deg_in[n] = din;
    norm_src[n] = dout > 0 ? rsqrtf((float)dout) : 0.f;
    norm_dst[n] = din > 0 ? rsqrtf((float)din) : 0.f;
  }
}

// ---------- 3-phase parallel scan of deg_in -> off, cursor ----------
__global__ __launch_bounds__(256) void k_scan1(const int* __restrict__ deg_in,
                                               int* __restrict__ partial, int N) {
  __shared__ int red[256];
  int t = threadIdx.x;
  int base = blockIdx.x * SCAN_CHUNK + t * 4;
  int s = 0;
#pragma unroll
  for (int i = 0; i < 4; ++i) {
    int idx = base + i;
    if (idx < N) s += deg_in[idx];
  }
  red[t] = s;
  __syncthreads();
  for (int d = 128; d > 0; d >>= 1) {
    if (t < d) red[t] += red[t + d];
    __syncthreads();
  }
  if (t == 0) partial[blockIdx.x] = red[0];
}

__global__ __launch_bounds__(1024) void k_scan2(int* __restrict__ partial, int B) {
  __shared__ int s[1024];
  int t = threadIdx.x;
  s[t] = (t < B) ? partial[t] : 0;
  __syncthreads();
  for (int d = 1; d < 1024; d <<= 1) {
    int v = (t >= d) ? s[t - d] : 0;
    __syncthreads();
    s[t] += v;
    __syncthreads();
  }
  if (t < B) partial[t] = (t == 0) ? 0 : s[t - 1];
}

__global__ __launch_bounds__(256) void k_scan3(const int* __restrict__ deg_in,
                                               const int* __restrict__ partial,
                                               int* __restrict__ off, int* __restrict__ cursor,
                                               int N) {
  __shared__ int red[256];
  int t = threadIdx.x;
  int base = blockIdx.x * SCAN_CHUNK + t * 4;
  int v[4];
  int s = 0;
#pragma unroll
  for (int i = 0; i < 4; ++i) {
    int idx = base + i;
    v[i] = (idx < N) ? deg_in[idx] : 0;
    s += v[i];
  }
  red[t] = s;
  __syncthreads();
  int own = s;
  for (int d = 1; d < 256; d <<= 1) {
    int u = (t >= d) ? red[t - d] : 0;
    __syncthreads();
    red[t] += u;
    __syncthreads();
  }
  int excl = red[t] - own + partial[blockIdx.x];
#pragma unroll
  for (int i = 0; i < 4; ++i) {
    int idx = base + i;
    if (idx < N) {
      off[idx] = excl;
      cursor[idx] = excl;
      excl += v[i];
      if (idx == N - 1) off[N] = excl;
    }
  }
}

// ---------- bucket edges by destination (device-scope: slot uniqueness is global) ----------
__global__ void k_bucket(const int* __restrict__ src, const int* __restrict__ dst,
                         int* __restrict__ cursor, int* __restrict__ esrc, int E) {
  int e = blockIdx.x * 256 + threadIdx.x;
  if (e < E) {
    int p = atomicAdd(&cursor[dst[e]], 1);
    esrc[p] = src[e];
  }
}

// ---------- GEMM1: h1n[n][c] = bf16( (sum_k x[n][k] W1[k][c]) * norm_src[n] ) ----------
__global__ __launch_bounds__(256) void k_gemm1(const float* __restrict__ x,
                                               const float* __restrict__ W1,
                                               const float* __restrict__ norm_src,
                                               unsigned short* __restrict__ h1n, int N) {
  __shared__ float Wlds[128 * 64];   // [k][cc]
  __shared__ float xsT[128 * 64];    // [k][r]
  int row0 = blockIdx.x * 64;
  int c0 = blockIdx.y * 64;
  int tid = threadIdx.x;

  for (int i = tid; i < 2048; i += 256) {
    int k = i >> 4;
    int cc = (i & 15) << 2;
    *(float4*)&Wlds[k * 64 + cc] = *(const float4*)&W1[k * 128 + c0 + cc];
  }
  for (int i = tid; i < 2048; i += 256) {
    int r = i & 63;
    int kb = (i >> 6) << 2;
    int grow = row0 + r;
    float4 v = make_float4(0.f, 0.f, 0.f, 0.f);
    if (grow < N) v = *(const float4*)&x[(size_t)grow * 128 + kb];
    xsT[(kb + 0) * 64 + r] = v.x;
    xsT[(kb + 1) * 64 + r] = v.y;
    xsT[(kb + 2) * 64 + r] = v.z;
    xsT[(kb + 3) * 64 + r] = v.w;
  }
  __syncthreads();

  int tc = tid & 15;
  int tr = tid >> 4;
  float acc[4][4] = {{0.f}};
#pragma unroll 4
  for (int k = 0; k < 128; ++k) {
    float4 xv = *(const float4*)&xsT[k * 64 + tr * 4];
    float4 wv = *(const float4*)&Wlds[k * 64 + tc * 4];
    acc[0][0] += xv.x * wv.x; acc[0][1] += xv.x * wv.y; acc[0][2] += xv.x * wv.z; acc[0][3] += xv.x * wv.w;
    acc[1][0] += xv.y * wv.x; acc[1][1] += xv.y * wv.y; acc[1][2] += xv.y * wv.z; acc[1][3] += xv.y * wv.w;
    acc[2][0] += xv.z * wv.x; acc[2][1] += xv.z * wv.y; acc[2][2] += xv.z * wv.z; acc[2][3] += xv.z * wv.w;
    acc[3][0] += xv.w * wv.x; acc[3][1] += xv.w * wv.y; acc[3][2] += xv.w * wv.z; acc[3][3] += xv.w * wv.w;
  }
#pragma unroll
  for (int i = 0; i < 4; ++i) {
    int grow = row0 + tr * 4 + i;
    if (grow < N) {
      float ns = norm_src[grow];
      ushort4 o;
      o.x = f2bf(acc[i][0] * ns);
      o.y = f2bf(acc[i][1] * ns);
      o.z = f2bf(acc[i][2] * ns);
      o.w = f2bf(acc[i][3] * ns);
      *(ushort4*)&h1n[(size_t)grow * 128 + c0 + tc * 4] = o;
    }
  }
}

// ---------- layer-1 aggregation: one wave per dst node, 4 edges in flight ----------
__global__ __launch_bounds__(256) void k_agg1(const unsigned short* __restrict__ h1n,
                                              const int* __restrict__ off,
                                              const int* __restrict__ esrc,
                                              const float* __restrict__ norm_dst,
                                              const float* __restrict__ b1,
                                              float* __restrict__ h1b, int N) {
  int wid = (blockIdx.x * 256 + threadIdx.x) >> 6;
  int lane = threadIdx.x & 63;
  if (wid >= N) return;
  int i0 = off[wid], i1 = off[wid + 1];
  int q = lane >> 4;
  int fl = lane & 15;
  float acc[8] = {0.f, 0.f, 0.f, 0.f, 0.f, 0.f, 0.f, 0.f};
  for (int i = i0; i < i1; i += 64) {
    int cnt = min(64, i1 - i);
    int eid = (i + lane < i1) ? esrc[i + lane] : -1;
    for (int t = 0; t < cnt; t += 4) {
      int s = __shfl(eid, t + q);
      if (s >= 0) {
        us8 v = *(const us8*)&h1n[(size_t)s * 128 + fl * 8];
#pragma unroll
        for (int j = 0; j < 8; ++j) acc[j] += bf2f(v[j]);
      }
    }
  }
#pragma unroll
  for (int j = 0; j < 8; ++j) acc[j] += __shfl_down(acc[j], 32);
#pragma unroll
  for (int j = 0; j < 8; ++j) acc[j] += __shfl_down(acc[j], 16);
  if (lane < 16) {
    float nd = norm_dst[wid];
    float4 b0 = *(const float4*)&b1[fl * 8];
    float4 b4 = *(const float4*)&b1[fl * 8 + 4];
    float4 o0, o4;
    o0.x = fmaxf(acc[0] * nd + b0.x, 0.f);
    o0.y = fmaxf(acc[1] * nd + b0.y, 0.f);
    o0.z = fmaxf(acc[2] * nd + b0.z, 0.f);
    o0.w = fmaxf(acc[3] * nd + b0.w, 0.f);
    o4.x = fmaxf(acc[4] * nd + b4.x, 0.f);
    o4.y = fmaxf(acc[5] * nd + b4.y, 0.f);
    o4.z = fmaxf(acc[6] * nd + b4.z, 0.f);
    o4.w = fmaxf(acc[7] * nd + b4.w, 0.f);
    *(float4*)&h1b[(size_t)wid * 128 + fl * 8] = o0;
    *(float4*)&h1b[(size_t)wid * 128 + fl * 8 + 4] = o4;
  }
}

// ---------- GEMM2 ----------
__global__ __launch_bounds__(256) void k_gemm2(const float* __restrict__ h1b,
                                               const float* __restrict__ W2,
                                               const float* __restrict__ norm_src,
                                               float* __restrict__ h2n, int N) {
  __shared__ float W2l[128 * 8];
  int tid = threadIdx.x;
  for (int i = tid; i < 1024; i += 256) W2l[i] = W2[i];
  __syncthreads();
  int g = blockIdx.x * 256 + tid;
  int node = g >> 3, j = g & 7;
  if (node >= N) return;
  const float* row = h1b + (size_t)node * 128;
  float acc = 0.f;
#pragma unroll
  for (int k = 0; k < 128; k += 4) {
    float4 v = *(const float4*)&row[k];
    acc += v.x * W2l[(k + 0) * 8 + j] + v.y * W2l[(k + 1) * 8 + j] +
           v.z * W2l[(k + 2) * 8 + j] + v.w * W2l[(k + 3) * 8 + j];
  }
  h2n[g] = acc * norm_src[node];
}

// ---------- layer-2 aggregation + mean-pool: LDS pre-reduction, few global atomics ----------
// Block covers 32 consecutive nodes; gids sorted -> usually 1-2 distinct graphs/block.
__global__ __launch_bounds__(256) void k_agg2pool(const float* __restrict__ h2n,
                                                  const int* __restrict__ off,
                                                  const int* __restrict__ esrc,
                                                  const float* __restrict__ norm_dst,
                                                  const float* __restrict__ b2,
                                                  const int* __restrict__ gids,
                                                  float* __restrict__ gsum, int N) {
  __shared__ float bins[16 * 8];
  __shared__ int sg0;
  int tid = threadIdx.x;
  if (tid < 128) bins[tid] = 0.f;
  int base = blockIdx.x * 32;
  if (tid == 0) sg0 = gids[min(base, N - 1)];
  __syncthreads();
  int node = base + (tid >> 3);
  int j = tid & 7;
  if (node < N) {
    int i0 = off[node], i1 = off[node + 1];
    float acc = 0.f;
    for (int i = i0; i < i1; i += 8) {
      int cnt = min(8, i1 - i);
      int eid = (i + j < i1) ? esrc[i + j] : 0;
      for (int t = 0; t < cnt; ++t) {
        int s = __shfl(eid, t, 8);
        acc += h2n[s * 8 + j];
      }
    }
    float r = acc * norm_dst[node] + b2[j];
    int delta = gids[node] - sg0;
    if (delta < 16) atomicAdd(&bins[delta * 8 + j], r);
    else atomicAdd(&gsum[gids[node] * 8 + j], r);   // rare fallback
  }
  __syncthreads();
  if (tid < 128) {
    float v = bins[tid];
    if (v != 0.f) atomicAdd(&gsum[(sg0 + (tid >> 3)) * 8 + (tid & 7)], v);
  }
}

// ---------- final: out = gsum / count, counts via binary search on sorted gids ----------
__global__ void k_final(const float* __restrict__ gsum, const int* __restrict__ gids,
                        float* __restrict__ out, int NG, int N) {
  int i = blockIdx.x * 256 + threadIdx.x;
  if (i < NG * F2) {
    int g = i >> 3;
    int lo = 0, hi = N;
    while (lo < hi) { int m = (lo + hi) >> 1; if (gids[m] < g) lo = m + 1; else hi = m; }
    int lb = lo;
    lo = 0; hi = N;
    while (lo < hi) { int m = (lo + hi) >> 1; if (gids[m] <= g) lo = m + 1; else hi = m; }
    int cnt = lo - lb;
    out[i] = gsum[i] / fmaxf((float)cnt, 1.f);
  }
}

extern "C" void kernel_launch(void* const* d_in, const int* in_sizes, int n_in,
                              void* d_out, int out_size, void* d_ws, size_t ws_size,
                              hipStream_t stream) {
  const float* x  = (const float*)d_in[0];
  const float* W1 = (const float*)d_in[1];
  const float* b1 = (const float*)d_in[2];
  const float* W2 = (const float*)d_in[3];
  const float* b2 = (const float*)d_in[4];
  const int* src  = (const int*)d_in[5];
  const int* dst  = (const int*)d_in[6];
  const int* gids = (const int*)d_in[7];
  int N = in_sizes[0] / F1;
  int E = in_sizes[5];
  int NG = out_size / F2;
  float* out = (float*)d_out;
  int Ns = (N + 63) & ~63;

  char* p = (char*)d_ws;
  auto alloc = [&](size_t bytes) -> void* {
    void* r = (void*)p;
    p += (bytes + 255) & ~(size_t)255;
    return r;
  };
  int* deg_out_r = (int*)alloc((size_t)NREP * Ns * 4);
  int* deg_in_r  = (int*)alloc((size_t)NREP * Ns * 4);
  float* gsum    = (float*)alloc((size_t)NG * F2 * 4);
  size_t zero_bytes = (size_t)((char*)p - (char*)deg_out_r);
  int* deg_in    = (int*)alloc((size_t)N * 4);
  float* norm_src = (float*)alloc((size_t)N * 4);
  float* norm_dst = (float*)alloc((size_t)N * 4);
  int* off       = (int*)alloc((size_t)(N + 1) * 4);
  int* cursor    = (int*)alloc((size_t)N * 4);
  int* esrc      = (int*)alloc((size_t)E * 4);
  int* partial   = (int*)alloc((size_t)1024 * 4);
  unsigned short* h1n = (unsigned short*)alloc((size_t)N * F1 * 2);
  float* h1b     = (float*)alloc((size_t)N * F1 * 4);
  float* h2n     = (float*)alloc((size_t)N * F2 * 4);
  (void)ws_size; (void)n_in;

  hipMemsetAsync(deg_out_r, 0, zero_bytes, stream);

  int B = (N + SCAN_CHUNK - 1) / SCAN_CHUNK;
  k_degrees<<<(E + 255) / 256, 256, 0, stream>>>(src, dst, deg_out_r, deg_in_r, E, Ns);
  k_norms<<<(N + 255) / 256, 256, 0, stream>>>(deg_out_r, deg_in_r, norm_src, norm_dst, deg_in, N, Ns);
  k_scan1<<<B, 256, 0, stream>>>(deg_in, partial, N);
  k_scan2<<<1, 1024, 0, stream>>>(partial, B);
  k_scan3<<<B, 256, 0, stream>>>(deg_in, partial, off, cursor, N);
  k_bucket<<<(E + 255) / 256, 256, 0, stream>>>(src, dst, cursor, esrc, E);
  k_gemm1<<<dim3((N + 63) / 64, 2), 256, 0, stream>>>(x, W1, norm_src, h1n, N);
  k_agg1<<<(N + 3) / 4, 256, 0, stream>>>(h1n, off, esrc, norm_dst, b1, h1b, N);
  k_gemm2<<<((size_t)N * 8 + 255) / 256, 256, 0, stream>>>(h1b, W2, norm_src, h2n, N);
  k_agg2pool<<<((N * 8 + 255) / 256), 256, 0, stream>>>(h2n, off, esrc, norm_dst, b2, gids, gsum, N);
  k_final<<<(NG * F2 + 255) / 256, 256, 0, stream>>>(gsum, gids, out, NG, N);
}